// Round 21
// baseline (106.767 us; speedup 1.0000x reference)
//
#include <hip/hip_runtime.h>

// SHToGridDensity: density[row][g] = sum_{lm,r} coeffs[row][lm][r]*Y[lm][g]*R[r][g]
// row in 0..255, g in 0..35936. Inputs f32; OUTPUT f32 (r9-verified).
//
// GEMM D[256][G] = A[256][K=400] x B[400][G] on mfma_f32_32x32x16_bf16.
// Per-lane operand map (shared bijection, r12..r20 on-device verified,
// absmax 0.125):
//   A: row = l&31 (+32*mt), elem j at k-local = (l>>5)*8 + j
//   B: col = l&31, same k-local map, in-register:
//      elem j = Y[lm][g] * R[(l>>5)*8+j][g], RNE via v_cvt_pk_bf16_f32
// D: col = l&31, row = (reg&3) + 8*(reg>>2) + 4*(l>>5)  [m74/m101 HW-verified]
//
// r21 (r20 post-mortem: 6 structural variants all 24.7-27.5us; latency-bound,
// phase-serial blocks run in 1.5-2.2 dispatch rounds):
//   SINGLE-ROUND RESIDENCY + DOUBLE-BUFFERED PIPELINE.
//   Block = 256 cols x m-tile PAIR processed sequentially:
//     stage A0 -> bar -> [stage A1 overlaps K0] -> K0 -> stores0 -> bar
//     -> K1 -> stores1.
//   Y/R registers shared across both tiles (same cols). LDS 2x25.6KB dbuf ->
//   3 blocks/CU; grid = 564 blocks <= 768 resident => NO dispatch rounds.
// Math bit-identical to r20.

#define G_TOTAL 35937

typedef __attribute__((ext_vector_type(8))) short bf16x8;
typedef __attribute__((ext_vector_type(16))) float f32x16;

__constant__ int c_lmFlat[25] = {4, 12,13,14, 20,21,22,23,24,
                                 28,29,30,31,32,33,34,
                                 36,37,38,39,40,41,42,43,44};

// Block = 256 threads = 4 waves; owns (col-slab cs: 256 cols) x (m-pair mp:
// m-tiles {2mp, 2mp+1}). Wave w -> cols [cs*256 + w*64, +64) as two 32-col
// slabs. grid = (141, 4) = 564 blocks, all co-resident at 3 blocks/CU.
__global__ __launch_bounds__(256, 3) void sh_fused(
        const float* __restrict__ coeffs,
        const float* __restrict__ Y,
        const float* __restrict__ Rb,
        float* __restrict__ out) {
    __shared__ uint4 Ads[2][25 * 64];          // 2 x 25600 B double buffer

    const int tx = threadIdx.x;
    const int l  = tx & 63;
    const int w  = tx >> 6;          // 0..3 (64-col group)
    const int cl = l & 31;
    const int kg = l >> 5;           // 0..1 k-group (r-half)

    const int cs  = blockIdx.x;
    const int mp  = blockIdx.y;      // m-pair: tiles {2mp, 2mp+1}
    const int mt0 = 2 * mp;
    const int mt1 = 2 * mp + 1;

    const int gbase = cs * 256;
    const int g0 = gbase + w * 64 + cl;              // slab 0
    const int g1 = g0 + 32;                          // slab 1
    const int gc0 = g0 < G_TOTAL ? g0 : G_TOTAL - 1;
    const int gc1 = g1 < G_TOTAL ? g1 : G_TOTAL - 1;

    constexpr int lmFlat[25] = {4, 12,13,14, 20,21,22,23,24,
                                28,29,30,31,32,33,34,
                                36,37,38,39,40,41,42,43,44};

    // ---- A stage helper: m-tile mt -> Ads[buf] (RNE bf16 fragments) ----
    // job j (0..1599): ks = j>>6, lane = j&63; 8 f32 -> 4 cvt_pk -> ds_write_b128
    auto stageA = [&](int mt, int buf) {
#pragma unroll
        for (int i = 0; i < 7; ++i) {
            int j = tx + i * 256;
            if (j < 1600) {
                int ks   = j >> 6;
                int lane = j & 63;
                const float* s = coeffs + (mt * 32 + (lane & 31)) * 720
                                 + lmFlat[ks] * 16 + (lane >> 5) * 8;
                float4 f0 = *(const float4*)s;
                float4 f1 = *(const float4*)(s + 4);
                unsigned u0, u1, u2, u3;
                asm("v_cvt_pk_bf16_f32 %0, %1, %2" : "=v"(u0) : "v"(f0.x), "v"(f0.y));
                asm("v_cvt_pk_bf16_f32 %0, %1, %2" : "=v"(u1) : "v"(f0.z), "v"(f0.w));
                asm("v_cvt_pk_bf16_f32 %0, %1, %2" : "=v"(u2) : "v"(f1.x), "v"(f1.y));
                asm("v_cvt_pk_bf16_f32 %0, %1, %2" : "=v"(u3) : "v"(f1.z), "v"(f1.w));
                Ads[buf][ks * 64 + lane] = make_uint4(u0, u1, u2, u3);
            }
        }
    };

    // ---- per-lane B-operand state: loaded ONCE, shared by both tiles ----
    float YA[25], YB[25];
#pragma unroll
    for (int i = 0; i < 25; ++i) {
        YA[i] = Y[lmFlat[i] * G_TOTAL + gc0];
        YB[i] = Y[lmFlat[i] * G_TOTAL + gc1];
    }
    float RA[8], RB[8];
#pragma unroll
    for (int j = 0; j < 8; ++j) {
        RA[j] = Rb[(kg * 8 + j) * G_TOTAL + gc0];
        RB[j] = Rb[(kg * 8 + j) * G_TOTAL + gc1];
    }

    // ---- K-loop + store helper for one tile ----
    auto tile = [&](int mt, int buf) {
        f32x16 acc0, acc1;
#pragma unroll
        for (int q = 0; q < 16; ++q) { acc0[q] = 0.0f; acc1[q] = 0.0f; }
        const bf16x8* __restrict__ Al = (const bf16x8*)Ads[buf];
#pragma unroll
        for (int ks = 0; ks < 25; ++ks) {
            const float y0 = YA[ks];
            const float y1 = YB[ks];
            union { unsigned int u[4]; bf16x8 v; } fb0, fb1;
#pragma unroll
            for (int p = 0; p < 4; ++p) {
                float a_lo = y0 * RA[2 * p], a_hi = y0 * RA[2 * p + 1];
                float b_lo = y1 * RB[2 * p], b_hi = y1 * RB[2 * p + 1];
                unsigned ra, rb;
                asm("v_cvt_pk_bf16_f32 %0, %1, %2" : "=v"(ra) : "v"(a_lo), "v"(a_hi));
                asm("v_cvt_pk_bf16_f32 %0, %1, %2" : "=v"(rb) : "v"(b_lo), "v"(b_hi));
                fb0.u[p] = ra;
                fb1.u[p] = rb;
            }
            bf16x8 a = Al[ks * 64 + l];
            acc0 = __builtin_amdgcn_mfma_f32_32x32x16_bf16(a, fb0.v, acc0, 0, 0, 0);
            acc1 = __builtin_amdgcn_mfma_f32_32x32x16_bf16(a, fb1.v, acc1, 0, 0, 0);
        }
        const int rbase = mt * 32 + 4 * kg;
        if (g0 < G_TOTAL) {
#pragma unroll
            for (int reg = 0; reg < 16; ++reg) {
                int ro = (reg & 3) + 8 * (reg >> 2);
                out[(size_t)(rbase + ro) * G_TOTAL + g0] = acc0[reg];
            }
        }
        if (g1 < G_TOTAL) {
#pragma unroll
            for (int reg = 0; reg < 16; ++reg) {
                int ro = (reg & 3) + 8 * (reg >> 2);
                out[(size_t)(rbase + ro) * G_TOTAL + g1] = acc1[reg];
            }
        }
    };

    // ---- pipelined schedule ----
    stageA(mt0, 0);          // stage tile 0
    __syncthreads();
    stageA(mt1, 1);          // tile 1 staging: global loads overlap K-loop 0
    tile(mt0, 0);            // compute + store tile 0
    __syncthreads();         // A1 ds_writes visible to all waves
    tile(mt1, 1);            // compute + store tile 1
}

extern "C" void kernel_launch(void* const* d_in, const int* in_sizes, int n_in,
                              void* d_out, int out_size, void* d_ws, size_t ws_size,
                              hipStream_t stream) {
    // pointer identification by element count (robust to dict-order changes)
    const float *pC = nullptr, *pY = nullptr, *pR = nullptr;
    if (n_in >= 3) {
        for (int i = 0; i < 3; ++i) {
            if      (in_sizes[i] == 256 * 720)    pC = (const float*)d_in[i];
            else if (in_sizes[i] == 45 * G_TOTAL) pY = (const float*)d_in[i];
            else if (in_sizes[i] == 16 * G_TOTAL) pR = (const float*)d_in[i];
        }
    }
    if (!pC || !pY || !pR) {
        pC = (const float*)d_in[0];
        pY = (const float*)d_in[1];
        pR = (const float*)d_in[2];
    }

    float* out = (float*)d_out;   // f32 output (r9-verified)

    dim3 grid(141, 4);   // 141 col-slabs x 4 m-pairs = 564 blocks, all resident
    sh_fused<<<grid, 256, 0, stream>>>(pC, pY, pR, out);

    (void)d_ws; (void)ws_size; (void)out_size; (void)n_in;
}

// Round 22
// 30.223 us; speedup vs baseline: 3.5326x; 3.5326x over previous
//
#include <hip/hip_runtime.h>

// SHToGridDensity: density[row][g] = sum_{lm,r} coeffs[row][lm][r]*Y[lm][g]*R[r][g]
// row in 0..255, g in 0..35936. Inputs f32; OUTPUT f32 (r9-verified).
//
// GEMM D[256][G] = A[256][K=400] x B[400][G] on mfma_f32_32x32x16_bf16.
// K = 25 lm-steps x 16 r: each MFMA consumes exactly one lm (no pad).
// Per-lane operand map (BOTH operands, shared bijection — r12..r20 on-device
// verified, absmax 0.125):
//   A: row = l&31 (+32*mt), elem j at k-local = (l>>5)*8 + j
//   B: col = l&31, same k-local map, in-register:
//      elem j = Y[lm][g] * R[(l>>5)*8+j][g], RNE via v_cvt_pk_bf16_f32
// D: col = l&31, row = (reg&3) + 8*(reg>>2) + 4*(l>>5)  [m74/m101 HW-verified]
//
// r22 = CHAMPION REVERT (r15 structure, 24.7us) + ONE variable:
//   NON-TEMPORAL STORES in the epilogue. Output is write-once/never-read;
//   plain stores write-allocate 36.9MB through the 4MB/XCD L2s, evicting the
//   read-side working set (kernel is latency-bound, r19 counters). nt stores
//   stream to HBM and keep L2 for coeffs/Y/R.
// r21 post-mortem: dbuf pipeline spilled (WRITE 202MB/FETCH 96MB = scratch
// traffic) -> refuted. Everything below except the store intrinsic is
// byte-identical to r15.

#define G_TOTAL 35937
#define N_ROWS  256

typedef __attribute__((ext_vector_type(8))) short bf16x8;
typedef __attribute__((ext_vector_type(16))) float f32x16;

__constant__ int c_lmFlat[25] = {4, 12,13,14, 20,21,22,23,24,
                                 28,29,30,31,32,33,34,
                                 36,37,38,39,40,41,42,43,44};

// Block = 512 threads = 8 waves. blockIdx.y -> m-tiles {2y,2y+1} (A staged
// from coeffs into LDS); wave w -> col-slab blockIdx.x*256 + w*32.
// grid = (ceil(35937/256)=141, 4).
__global__ __launch_bounds__(512, 4) void sh_fused(
        const float* __restrict__ coeffs,
        const float* __restrict__ Y,
        const float* __restrict__ Rb,
        float* __restrict__ out) {
    __shared__ uint4 Alds[50 * 64];            // 51200 B: [ks*2+mtl][lane]
    const int tx = threadIdx.x;
    const int l  = tx & 63;
    const int w  = tx >> 6;          // 0..7 col-slab
    const int cl = l & 31;
    const int kg = l >> 5;           // 0..1 k-group

    const int bY = blockIdx.y;       // m-pair: global m-tiles {2bY, 2bY+1}
    const int g  = blockIdx.x * 256 + w * 32 + cl;
    const int gc = g < G_TOTAL ? g : G_TOTAL - 1;

    // ---- fused A stage: raw coeffs f32 -> RNE bf16 fragments in LDS ----
    // chunk c (0..1599): ks = c>>6, rowl = c&63. 16 f32 at
    // coeffs[(bY*64+rowl)*720 + lmFlat[ks]*16] -> 8 cvt_pk -> 2 ds_write_b128.
#pragma unroll
    for (int i = 0; i < 4; ++i) {
        int c = tx + i * 512;
        if (c < 1600) {
            int ks   = c >> 6;
            int rowl = c & 63;
            int mtl  = rowl >> 5;
            int r32  = rowl & 31;
            const float4* src = (const float4*)(coeffs + (bY * 64 + rowl) * 720
                                                + c_lmFlat[ks] * 16);
            float4 f0 = src[0], f1 = src[1], f2 = src[2], f3 = src[3];
            unsigned u0, u1, u2, u3, u4, u5, u6, u7;
            asm("v_cvt_pk_bf16_f32 %0, %1, %2" : "=v"(u0) : "v"(f0.x), "v"(f0.y));
            asm("v_cvt_pk_bf16_f32 %0, %1, %2" : "=v"(u1) : "v"(f0.z), "v"(f0.w));
            asm("v_cvt_pk_bf16_f32 %0, %1, %2" : "=v"(u2) : "v"(f1.x), "v"(f1.y));
            asm("v_cvt_pk_bf16_f32 %0, %1, %2" : "=v"(u3) : "v"(f1.z), "v"(f1.w));
            asm("v_cvt_pk_bf16_f32 %0, %1, %2" : "=v"(u4) : "v"(f2.x), "v"(f2.y));
            asm("v_cvt_pk_bf16_f32 %0, %1, %2" : "=v"(u5) : "v"(f2.z), "v"(f2.w));
            asm("v_cvt_pk_bf16_f32 %0, %1, %2" : "=v"(u6) : "v"(f3.x), "v"(f3.y));
            asm("v_cvt_pk_bf16_f32 %0, %1, %2" : "=v"(u7) : "v"(f3.z), "v"(f3.w));
            int fbase = (ks * 2 + mtl) * 64;
            Alds[fbase + r32]      = make_uint4(u0, u1, u2, u3);  // kg=0 lane
            Alds[fbase + 32 + r32] = make_uint4(u4, u5, u6, u7);  // kg=1 lane
        }
    }

    // ---- per-lane B-operand state (overlaps with staging loads) ----
    constexpr int lmFlat[25] = {4, 12,13,14, 20,21,22,23,24,
                                28,29,30,31,32,33,34,
                                36,37,38,39,40,41,42,43,44};
    float YA[25];
#pragma unroll
    for (int i = 0; i < 25; ++i) YA[i] = Y[lmFlat[i] * G_TOTAL + gc];

    float RA[8];
#pragma unroll
    for (int j = 0; j < 8; ++j) RA[j] = Rb[(kg * 8 + j) * G_TOTAL + gc];

    f32x16 acc0, acc1;
#pragma unroll
    for (int q = 0; q < 16; ++q) { acc0[q] = 0.0f; acc1[q] = 0.0f; }

    __syncthreads();

    // ---- K-loop: 25 steps, A from LDS (ds_read_b128, conflict-free) ----
    const bf16x8* __restrict__ Al = (const bf16x8*)Alds;
#pragma unroll
    for (int ks = 0; ks < 25; ++ks) {
        const float y = YA[ks];
        union { unsigned int u[4]; bf16x8 v; } fb;
#pragma unroll
        for (int p = 0; p < 4; ++p) {
            float lo = y * RA[2 * p];
            float hi = y * RA[2 * p + 1];
            unsigned r;
            asm("v_cvt_pk_bf16_f32 %0, %1, %2" : "=v"(r) : "v"(lo), "v"(hi));
            fb.u[p] = r;   // elem 2p in [15:0], 2p+1 in [31:16] == stage order
        }
        bf16x8 a0 = Al[(ks * 2 + 0) * 64 + l];
        bf16x8 a1 = Al[(ks * 2 + 1) * 64 + l];
        acc0 = __builtin_amdgcn_mfma_f32_32x32x16_bf16(a0, fb.v, acc0, 0, 0, 0);
        acc1 = __builtin_amdgcn_mfma_f32_32x32x16_bf16(a1, fb.v, acc1, 0, 0, 0);
    }

    // ---- epilogue: NON-TEMPORAL stores (the one change vs r15) ----
    if (g < G_TOTAL) {
        const int rb0 = (2 * bY)     * 32 + 4 * kg;
        const int rb1 = (2 * bY + 1) * 32 + 4 * kg;
#pragma unroll
        for (int reg = 0; reg < 16; ++reg) {
            int ro = (reg & 3) + 8 * (reg >> 2);
            __builtin_nontemporal_store(acc0[reg],
                &out[(size_t)(rb0 + ro) * G_TOTAL + g]);
            __builtin_nontemporal_store(acc1[reg],
                &out[(size_t)(rb1 + ro) * G_TOTAL + g]);
        }
    }
}

extern "C" void kernel_launch(void* const* d_in, const int* in_sizes, int n_in,
                              void* d_out, int out_size, void* d_ws, size_t ws_size,
                              hipStream_t stream) {
    // pointer identification by element count (robust to dict-order changes)
    const float *pC = nullptr, *pY = nullptr, *pR = nullptr;
    if (n_in >= 3) {
        for (int i = 0; i < 3; ++i) {
            if      (in_sizes[i] == 256 * 720)    pC = (const float*)d_in[i];
            else if (in_sizes[i] == 45 * G_TOTAL) pY = (const float*)d_in[i];
            else if (in_sizes[i] == 16 * G_TOTAL) pR = (const float*)d_in[i];
        }
    }
    if (!pC || !pY || !pR) {
        pC = (const float*)d_in[0];
        pY = (const float*)d_in[1];
        pR = (const float*)d_in[2];
    }

    float* out = (float*)d_out;   // f32 output (r9-verified)

    dim3 grid(141, 4);
    sh_fused<<<grid, 512, 0, stream>>>(pC, pY, pR, out);

    (void)d_ws; (void)ws_size; (void)out_size; (void)n_in;
}

// Round 23
// 26.233 us; speedup vs baseline: 4.0699x; 1.1521x over previous
//
#include <hip/hip_runtime.h>

// SHToGridDensity: density[row][g] = sum_{lm,r} coeffs[row][lm][r]*Y[lm][g]*R[r][g]
// row in 0..255, g in 0..35936. Inputs f32; OUTPUT f32 (r9-verified).
//
// GEMM D[256][G] = A[256][K=400] x B[400][G] on mfma_f32_32x32x16_bf16.
// K = 25 lm-steps x 16 r: each MFMA consumes exactly one lm (no pad).
// Per-lane operand map (BOTH operands, shared bijection — r12..r22 on-device
// verified, absmax 0.125):
//   A: row = l&31 (+32*mt), elem j at k-local = (l>>5)*8 + j
//   B: col = l&31, same k-local map, in-register:
//      elem j = Y[lm][g] * R[(l>>5)*8+j][g], RNE via v_cvt_pk_bf16_f32
// D: col = l&31, row = (reg&3) + 8*(reg>>2) + 4*(l>>5)  [m74/m101 HW-verified]
//
// r23 = CHAMPION RESTORE (r15, 24.7us — best of 9 structural variants).
// Only delta vs r15: Y/R loads issued BEFORE the staging loop (issue-order
// hint; independent loads, zero structural risk).
// Ledger of falsified theories: LDS-traffic (r16), Y-LDS+XCD-swizzle (r17),
// store coalescing (r18), occupancy/barriers (r20), dbuf pipeline (r21,
// spill), nt stores (r22). r19 fit: ~15.5us marginal + ~10us fixed;
// counters show no pipe >30% => latency-bound floor at this structure.

#define G_TOTAL 35937
#define N_ROWS  256

typedef __attribute__((ext_vector_type(8))) short bf16x8;
typedef __attribute__((ext_vector_type(16))) float f32x16;

__constant__ int c_lmFlat[25] = {4, 12,13,14, 20,21,22,23,24,
                                 28,29,30,31,32,33,34,
                                 36,37,38,39,40,41,42,43,44};

// Block = 512 threads = 8 waves. blockIdx.y -> m-tiles {2y,2y+1} (A staged
// from coeffs into LDS); wave w -> col-slab blockIdx.x*256 + w*32.
// grid = (ceil(35937/256)=141, 4) = 564 blocks, single dispatch round.
__global__ __launch_bounds__(512, 4) void sh_fused(
        const float* __restrict__ coeffs,
        const float* __restrict__ Y,
        const float* __restrict__ Rb,
        float* __restrict__ out) {
    __shared__ uint4 Alds[50 * 64];            // 51200 B: [ks*2+mtl][lane]
    const int tx = threadIdx.x;
    const int l  = tx & 63;
    const int w  = tx >> 6;          // 0..7 col-slab
    const int cl = l & 31;
    const int kg = l >> 5;           // 0..1 k-group

    const int bY = blockIdx.y;       // m-pair: global m-tiles {2bY, 2bY+1}
    const int g  = blockIdx.x * 256 + w * 32 + cl;
    const int gc = g < G_TOTAL ? g : G_TOTAL - 1;

    constexpr int lmFlat[25] = {4, 12,13,14, 20,21,22,23,24,
                                28,29,30,31,32,33,34,
                                36,37,38,39,40,41,42,43,44};

    // ---- per-lane B-operand state: issued FIRST (independent of staging) ----
    float YA[25];
#pragma unroll
    for (int i = 0; i < 25; ++i) YA[i] = Y[lmFlat[i] * G_TOTAL + gc];

    float RA[8];
#pragma unroll
    for (int j = 0; j < 8; ++j) RA[j] = Rb[(kg * 8 + j) * G_TOTAL + gc];

    // ---- fused A stage: raw coeffs f32 -> RNE bf16 fragments in LDS ----
    // chunk c (0..1599): ks = c>>6, rowl = c&63. 16 f32 at
    // coeffs[(bY*64+rowl)*720 + lmFlat[ks]*16] -> 8 cvt_pk -> 2 ds_write_b128.
#pragma unroll
    for (int i = 0; i < 4; ++i) {
        int c = tx + i * 512;
        if (c < 1600) {
            int ks   = c >> 6;
            int rowl = c & 63;
            int mtl  = rowl >> 5;
            int r32  = rowl & 31;
            const float4* src = (const float4*)(coeffs + (bY * 64 + rowl) * 720
                                                + lmFlat[ks] * 16);
            float4 f0 = src[0], f1 = src[1], f2 = src[2], f3 = src[3];
            unsigned u0, u1, u2, u3, u4, u5, u6, u7;
            asm("v_cvt_pk_bf16_f32 %0, %1, %2" : "=v"(u0) : "v"(f0.x), "v"(f0.y));
            asm("v_cvt_pk_bf16_f32 %0, %1, %2" : "=v"(u1) : "v"(f0.z), "v"(f0.w));
            asm("v_cvt_pk_bf16_f32 %0, %1, %2" : "=v"(u2) : "v"(f1.x), "v"(f1.y));
            asm("v_cvt_pk_bf16_f32 %0, %1, %2" : "=v"(u3) : "v"(f1.z), "v"(f1.w));
            asm("v_cvt_pk_bf16_f32 %0, %1, %2" : "=v"(u4) : "v"(f2.x), "v"(f2.y));
            asm("v_cvt_pk_bf16_f32 %0, %1, %2" : "=v"(u5) : "v"(f2.z), "v"(f2.w));
            asm("v_cvt_pk_bf16_f32 %0, %1, %2" : "=v"(u6) : "v"(f3.x), "v"(f3.y));
            asm("v_cvt_pk_bf16_f32 %0, %1, %2" : "=v"(u7) : "v"(f3.z), "v"(f3.w));
            int fbase = (ks * 2 + mtl) * 64;
            Alds[fbase + r32]      = make_uint4(u0, u1, u2, u3);  // kg=0 lane
            Alds[fbase + 32 + r32] = make_uint4(u4, u5, u6, u7);  // kg=1 lane
        }
    }

    f32x16 acc0, acc1;
#pragma unroll
    for (int q = 0; q < 16; ++q) { acc0[q] = 0.0f; acc1[q] = 0.0f; }

    __syncthreads();

    // ---- K-loop: 25 steps, A from LDS (ds_read_b128, conflict-free) ----
    const bf16x8* __restrict__ Al = (const bf16x8*)Alds;
#pragma unroll
    for (int ks = 0; ks < 25; ++ks) {
        const float y = YA[ks];
        union { unsigned int u[4]; bf16x8 v; } fb;
#pragma unroll
        for (int p = 0; p < 4; ++p) {
            float lo = y * RA[2 * p];
            float hi = y * RA[2 * p + 1];
            unsigned r;
            asm("v_cvt_pk_bf16_f32 %0, %1, %2" : "=v"(r) : "v"(lo), "v"(hi));
            fb.u[p] = r;   // elem 2p in [15:0], 2p+1 in [31:16] == stage order
        }
        bf16x8 a0 = Al[(ks * 2 + 0) * 64 + l];
        bf16x8 a1 = Al[(ks * 2 + 1) * 64 + l];
        acc0 = __builtin_amdgcn_mfma_f32_32x32x16_bf16(a0, fb.v, acc0, 0, 0, 0);
        acc1 = __builtin_amdgcn_mfma_f32_32x32x16_bf16(a1, fb.v, acc1, 0, 0, 0);
    }

    // ---- epilogue (r15 pattern: plain dword stores) ----
    if (g < G_TOTAL) {
        const int rb0 = (2 * bY)     * 32 + 4 * kg;
        const int rb1 = (2 * bY + 1) * 32 + 4 * kg;
#pragma unroll
        for (int reg = 0; reg < 16; ++reg) {
            int ro = (reg & 3) + 8 * (reg >> 2);
            out[(size_t)(rb0 + ro) * G_TOTAL + g] = acc0[reg];
            out[(size_t)(rb1 + ro) * G_TOTAL + g] = acc1[reg];
        }
    }
}

extern "C" void kernel_launch(void* const* d_in, const int* in_sizes, int n_in,
                              void* d_out, int out_size, void* d_ws, size_t ws_size,
                              hipStream_t stream) {
    // pointer identification by element count (robust to dict-order changes)
    const float *pC = nullptr, *pY = nullptr, *pR = nullptr;
    if (n_in >= 3) {
        for (int i = 0; i < 3; ++i) {
            if      (in_sizes[i] == 256 * 720)    pC = (const float*)d_in[i];
            else if (in_sizes[i] == 45 * G_TOTAL) pY = (const float*)d_in[i];
            else if (in_sizes[i] == 16 * G_TOTAL) pR = (const float*)d_in[i];
        }
    }
    if (!pC || !pY || !pR) {
        pC = (const float*)d_in[0];
        pY = (const float*)d_in[1];
        pR = (const float*)d_in[2];
    }

    float* out = (float*)d_out;   // f32 output (r9-verified)

    dim3 grid(141, 4);
    sh_fused<<<grid, 512, 0, stream>>>(pC, pY, pR, out);

    (void)d_ws; (void)ws_size; (void)out_size; (void)n_in;
}